// Round 1
// baseline (239.809 us; speedup 1.0000x reference)
//
#include <hip/hip_runtime.h>
#include <math.h>

// Problem constants (from reference): inp [16384,2048] f32, W [64,2048] f32, b [64] f32
// gate = inp @ W^T + b ; top-2 over 64 experts ; softmax over the 2 vals.
// d_out layout (float32): [tokens*2] indices (as floats), then [tokens*2] scores.

#define KDIM 2048
#define NEXP 64
#define BK 32
#define TM 64
#define LDSS 68   // 64 + 4 pad: 68*4=272 B row stride, multiple of 16 -> b128-aligned reads

__global__ __launch_bounds__(256) void gate_topk_kernel(
    const float* __restrict__ inp,
    const float* __restrict__ W,
    const float* __restrict__ bias,
    float* __restrict__ out,
    int tokens)
{
    __shared__ float As[BK][LDSS];   // As[k][token]   (token local 0..63)
    __shared__ float Ws[BK][LDSS];   // Ws[k][expert]

    const int tid = threadIdx.x;
    const int tx  = tid & 15;   // expert group: experts 4*tx .. 4*tx+3
    const int ty  = tid >> 4;   // token group:  tokens  4*ty .. 4*ty+3
    const int tokBase = blockIdx.x * TM;

    // Staging-load mapping: 256 threads load a 64-row x 32-col f32 tile as 2 passes
    // of float4; row = tid>>3 (+32), col = (tid&7)*4. Coalesced 16B/lane.
    const int lrow = tid >> 3;          // 0..31
    const int lcol = (tid & 7) << 2;    // 0,4,...,28

    const float* aPtr0 = inp + (size_t)(tokBase + lrow)      * KDIM + lcol;
    const float* aPtr1 = inp + (size_t)(tokBase + lrow + 32) * KDIM + lcol;
    const float* wPtr0 = W   + (size_t)lrow        * KDIM + lcol;
    const float* wPtr1 = W   + (size_t)(lrow + 32) * KDIM + lcol;

    float4 aReg0, aReg1, wReg0, wReg1;
    aReg0 = *(const float4*)(aPtr0);
    aReg1 = *(const float4*)(aPtr1);
    wReg0 = *(const float4*)(wPtr0);
    wReg1 = *(const float4*)(wPtr1);

    float acc[4][4];
    #pragma unroll
    for (int r = 0; r < 4; ++r)
        #pragma unroll
        for (int c = 0; c < 4; ++c) acc[r][c] = 0.0f;

    const int NT = KDIM / BK;   // 64 k-tiles
    for (int kt = 0; kt < NT; ++kt) {
        __syncthreads();   // previous tile's compute done before overwrite
        // transpose-store prefetched regs to LDS
        #pragma unroll
        for (int c = 0; c < 4; ++c) {
            As[lcol + c][lrow]      = ((const float*)&aReg0)[c];
            As[lcol + c][lrow + 32] = ((const float*)&aReg1)[c];
            Ws[lcol + c][lrow]      = ((const float*)&wReg0)[c];
            Ws[lcol + c][lrow + 32] = ((const float*)&wReg1)[c];
        }
        __syncthreads();
        // issue next tile's global loads; they fly during compute below
        if (kt + 1 < NT) {
            const int off = (kt + 1) * BK;
            aReg0 = *(const float4*)(aPtr0 + off);
            aReg1 = *(const float4*)(aPtr1 + off);
            wReg0 = *(const float4*)(wPtr0 + off);
            wReg1 = *(const float4*)(wPtr1 + off);
        }
        #pragma unroll 8
        for (int kk = 0; kk < BK; ++kk) {
            const float4 av = *(const float4*)&As[kk][ty << 2];
            const float4 wv = *(const float4*)&Ws[kk][tx << 2];
            const float a[4] = {av.x, av.y, av.z, av.w};
            const float w[4] = {wv.x, wv.y, wv.z, wv.w};
            #pragma unroll
            for (int r = 0; r < 4; ++r)
                #pragma unroll
                for (int c = 0; c < 4; ++c)
                    acc[r][c] = fmaf(a[r], w[c], acc[r][c]);
        }
    }

    // ---- epilogue: bias + top-2 + softmax ----
    const int eBase = tx << 2;
    float bv[4];
    #pragma unroll
    for (int c = 0; c < 4; ++c) bv[c] = bias[eBase + c];

    const int scoreOff = tokens * 2;   // indices occupy first tokens*2 floats

    #pragma unroll
    for (int r = 0; r < 4; ++r) {
        // local top-2 among this thread's 4 experts (ascending id scan keeps
        // lower index on ties, matching lax.top_k)
        float v1 = acc[r][0] + bv[0]; int i1 = eBase;
        float v2 = -INFINITY;         int i2 = -1;
        #pragma unroll
        for (int c = 1; c < 4; ++c) {
            const float vv = acc[r][c] + bv[c];
            const int   ii = eBase + c;
            if (vv > v1)      { v2 = v1; i2 = i1; v1 = vv; i1 = ii; }
            else if (vv > v2) { v2 = vv; i2 = ii; }
        }
        // butterfly merge across the 16 lanes sharing this token row
        #pragma unroll
        for (int m = 1; m <= 8; m <<= 1) {
            const float ov1 = __shfl_xor(v1, m);
            const int   oi1 = __shfl_xor(i1, m);
            const float ov2 = __shfl_xor(v2, m);
            const int   oi2 = __shfl_xor(i2, m);
            const bool aw = (v1 > ov1) || (v1 == ov1 && i1 < oi1);
            const float nv1 = aw ? v1  : ov1;  const int ni1 = aw ? i1  : oi1;
            const float lv  = aw ? ov1 : v1;   const int li  = aw ? oi1 : i1;  // loser of firsts
            const float sv  = aw ? v2  : ov2;  const int si  = aw ? i2  : oi2; // winner's second
            const bool sw = (sv > lv) || (sv == lv && si < li);
            v1 = nv1; i1 = ni1;
            v2 = sw ? sv : lv; i2 = sw ? si : li;
        }
        if (tx == 0) {
            const int token = tokBase + (ty << 2) + r;
            const float e2 = expf(v2 - v1);
            const float denom = 1.0f + e2;
            const float p1 = 1.0f / denom;
            const float p2 = e2 / denom;
            out[2 * token]     = (float)i1;
            out[2 * token + 1] = (float)i2;
            out[scoreOff + 2 * token]     = p1;
            out[scoreOff + 2 * token + 1] = p2;
        }
    }
}

extern "C" void kernel_launch(void* const* d_in, const int* in_sizes, int n_in,
                              void* d_out, int out_size, void* d_ws, size_t ws_size,
                              hipStream_t stream) {
    const float* inp  = (const float*)d_in[0];
    const float* W    = (const float*)d_in[1];
    const float* bias = (const float*)d_in[2];
    float* out = (float*)d_out;

    const int tokens = in_sizes[0] / KDIM;   // 16384
    const int grid = tokens / TM;            // 256 blocks

    gate_topk_kernel<<<grid, 256, 0, stream>>>(inp, W, bias, out, tokens);
}

// Round 2
// 218.167 us; speedup vs baseline: 1.0992x; 1.0992x over previous
//
#include <hip/hip_runtime.h>
#include <math.h>

// MoE gate: gate = inp[16384,2048]f32 @ W[64,2048]^T + b[64]; top-2; softmax.
// d_out (float32): [tokens*2] indices-as-floats, then [tokens*2] scores.
//
// Round 2: K-split x4. Round-1 counters: Occupancy 10.5% (1 block/CU),
// VALUBusy 31% == fp32 compute floor -> latency-bound. Splitting K keeps the
// 4x4 per-thread blocking (2 B LDS per FMA) while giving 4 blocks/CU.

#define KDIM 2048
#define NEXP 64
#define TM 64
#define BK 32
#define LDSS 68   // 64 + 4 pad: 272 B row stride (mult of 16 -> b128-aligned)

__global__ __launch_bounds__(256) void gate_partial_kernel(
    const float* __restrict__ inp,
    const float* __restrict__ W,
    float* __restrict__ partial,   // [S][tokens][NEXP]
    int tokens, int kPerSplit)
{
    __shared__ float As[BK][LDSS];   // As[k][token]
    __shared__ float Ws[BK][LDSS];   // Ws[k][expert]

    const int tid = threadIdx.x;
    const int tx  = tid & 15;        // experts 4*tx..4*tx+3
    const int ty  = tid >> 4;        // tokens 4*ty..4*ty+3
    const int tokBase = blockIdx.x * TM;
    const int split   = blockIdx.y;
    const int k0      = split * kPerSplit;

    // staging map: 64 rows x 32 cols f32 per tile, 2 passes of float4
    const int lrow = tid >> 3;          // 0..31
    const int lcol = (tid & 7) << 2;    // 0,4,...,28

    const float* aPtr0 = inp + (size_t)(tokBase + lrow)      * KDIM + k0 + lcol;
    const float* aPtr1 = inp + (size_t)(tokBase + lrow + 32) * KDIM + k0 + lcol;
    const float* wPtr0 = W   + (size_t)lrow        * KDIM + k0 + lcol;
    const float* wPtr1 = W   + (size_t)(lrow + 32) * KDIM + k0 + lcol;

    float4 aReg0 = *(const float4*)(aPtr0);
    float4 aReg1 = *(const float4*)(aPtr1);
    float4 wReg0 = *(const float4*)(wPtr0);
    float4 wReg1 = *(const float4*)(wPtr1);

    float acc[4][4];
    #pragma unroll
    for (int r = 0; r < 4; ++r)
        #pragma unroll
        for (int c = 0; c < 4; ++c) acc[r][c] = 0.0f;

    const int NT = kPerSplit / BK;
    for (int kt = 0; kt < NT; ++kt) {
        __syncthreads();
        #pragma unroll
        for (int c = 0; c < 4; ++c) {
            As[lcol + c][lrow]      = ((const float*)&aReg0)[c];
            As[lcol + c][lrow + 32] = ((const float*)&aReg1)[c];
            Ws[lcol + c][lrow]      = ((const float*)&wReg0)[c];
            Ws[lcol + c][lrow + 32] = ((const float*)&wReg1)[c];
        }
        __syncthreads();
        if (kt + 1 < NT) {
            const int off = (kt + 1) * BK;
            aReg0 = *(const float4*)(aPtr0 + off);
            aReg1 = *(const float4*)(aPtr1 + off);
            wReg0 = *(const float4*)(wPtr0 + off);
            wReg1 = *(const float4*)(wPtr1 + off);
        }
        #pragma unroll 8
        for (int kk = 0; kk < BK; ++kk) {
            const float4 av = *(const float4*)&As[kk][ty << 2];
            const float4 wv = *(const float4*)&Ws[kk][tx << 2];
            const float a[4] = {av.x, av.y, av.z, av.w};
            const float w[4] = {wv.x, wv.y, wv.z, wv.w};
            #pragma unroll
            for (int r = 0; r < 4; ++r)
                #pragma unroll
                for (int c = 0; c < 4; ++c)
                    acc[r][c] = fmaf(a[r], w[c], acc[r][c]);
        }
    }

    // write partials: [split][token][expert], float4 over experts, coalesced in tx
    const int eBase = tx << 2;
    #pragma unroll
    for (int r = 0; r < 4; ++r) {
        const int token = tokBase + (ty << 2) + r;
        float4 v = make_float4(acc[r][0], acc[r][1], acc[r][2], acc[r][3]);
        *(float4*)&partial[((size_t)split * tokens + token) * NEXP + eBase] = v;
    }
}

__global__ __launch_bounds__(256) void reduce_topk_kernel(
    const float* __restrict__ partial,
    const float* __restrict__ bias,
    float* __restrict__ out,
    int tokens, int S)
{
    const int tid = threadIdx.x;
    const int tx  = tid & 15;          // experts 4*tx..4*tx+3
    const int ty  = tid >> 4;          // 16 tokens per block
    const int token = blockIdx.x * 16 + ty;
    const int eBase = tx << 2;

    float4 v = make_float4(0.f, 0.f, 0.f, 0.f);
    for (int s = 0; s < S; ++s) {
        const float4 p = *(const float4*)&partial[((size_t)s * tokens + token) * NEXP + eBase];
        v.x += p.x; v.y += p.y; v.z += p.z; v.w += p.w;
    }
    const float4 bv = *(const float4*)&bias[eBase];
    float g[4] = { v.x + bv.x, v.y + bv.y, v.z + bv.z, v.w + bv.w };

    // local top-2 (ascending scan keeps lower index on ties, matching lax.top_k)
    float v1 = g[0]; int i1 = eBase;
    float v2 = -INFINITY; int i2 = -1;
    #pragma unroll
    for (int c = 1; c < 4; ++c) {
        const float vv = g[c];
        const int   ii = eBase + c;
        if (vv > v1)      { v2 = v1; i2 = i1; v1 = vv; i1 = ii; }
        else if (vv > v2) { v2 = vv; i2 = ii; }
    }
    // 16-lane butterfly merge
    #pragma unroll
    for (int m = 1; m <= 8; m <<= 1) {
        const float ov1 = __shfl_xor(v1, m);
        const int   oi1 = __shfl_xor(i1, m);
        const float ov2 = __shfl_xor(v2, m);
        const int   oi2 = __shfl_xor(i2, m);
        const bool aw = (v1 > ov1) || (v1 == ov1 && i1 < oi1);
        const float nv1 = aw ? v1  : ov1;  const int ni1 = aw ? i1  : oi1;
        const float lv  = aw ? ov1 : v1;   const int li  = aw ? oi1 : i1;
        const float sv  = aw ? v2  : ov2;  const int si  = aw ? i2  : oi2;
        const bool sw = (sv > lv) || (sv == lv && si < li);
        v1 = nv1; i1 = ni1;
        v2 = sw ? sv : lv; i2 = sw ? si : li;
    }
    if (tx == 0) {
        const float e2 = expf(v2 - v1);
        const float denom = 1.0f + e2;
        out[2 * token]     = (float)i1;
        out[2 * token + 1] = (float)i2;
        out[tokens * 2 + 2 * token]     = 1.0f / denom;
        out[tokens * 2 + 2 * token + 1] = e2 / denom;
    }
}

extern "C" void kernel_launch(void* const* d_in, const int* in_sizes, int n_in,
                              void* d_out, int out_size, void* d_ws, size_t ws_size,
                              hipStream_t stream) {
    const float* inp  = (const float*)d_in[0];
    const float* W    = (const float*)d_in[1];
    const float* bias = (const float*)d_in[2];
    float* out = (float*)d_out;
    float* partial = (float*)d_ws;

    const int tokens = in_sizes[0] / KDIM;   // 16384

    // pick largest split S in {4,2,1} whose partial buffer fits d_ws
    int S = 4;
    while (S > 1 && (size_t)S * tokens * NEXP * sizeof(float) > ws_size) S >>= 1;
    const int kPerSplit = KDIM / S;

    dim3 grid(tokens / TM, S);
    gate_partial_kernel<<<grid, 256, 0, stream>>>(inp, W, partial, tokens, kPerSplit);
    reduce_topk_kernel<<<tokens / 16, 256, 0, stream>>>(partial, bias, out, tokens, S);
}